// Round 2
// baseline (223.382 us; speedup 1.0000x reference)
//
#include <hip/hip_runtime.h>
#include <hip/hip_bf16.h>

#define B_ROWS 131072
#define H 128
#define BM 32
#define TILES 8
#define NBLK (B_ROWS / (BM * TILES))   // 512 blocks

typedef __bf16 bf16x8 __attribute__((ext_vector_type(8)));
typedef float f32x4 __attribute__((ext_vector_type(4)));

struct WPtrs {
    const float* wx[4];
    const float* wh[4];
    const float* bx[4];
    const float* bh[4];
};

// Wcat[n][k]: n = gate*128 + hidden_unit, k in [0,256) = [X-k | h-k]. bsum[n] = bx+bh.
__global__ __launch_bounds__(256) void prep_weights(WPtrs p, __bf16* __restrict__ wcat,
                                                    float* __restrict__ bsum) {
    int n = blockIdx.x;      // 0..511
    int k = threadIdx.x;     // 0..255
    int g = n >> 7, r = n & 127;
    float v = (k < H) ? p.wx[g][r * H + k] : p.wh[g][r * H + (k - H)];
    wcat[n * 256 + k] = (__bf16)v;
    if (k == 0) bsum[n] = p.bx[g][r] + p.bh[g][r];
}

__global__ __launch_bounds__(512, 4) void lstm_fused(
    const float* __restrict__ X, const float* __restrict__ Hp, const float* __restrict__ Cp,
    const __bf16* __restrict__ Wcat, const float* __restrict__ Bsum,
    float* __restrict__ out)
{
    // double-buffered 32-row x 256-col bf16 tile (512 B/row), XOR-swizzled
    __shared__ char lds[2][BM * 512];
    const int t = threadIdx.x;
    const int lane = t & 63;
    const int wv = t >> 6;                 // wave 0..7 -> hidden cols [wv*16, wv*16+16)
    const int l16 = lane & 15;
    const int kg = lane >> 4;
    const long base = (long)blockIdx.x * (BM * TILES);

    const int j = wv * 16 + l16;           // this lane's hidden column
    const __bf16* wbase = Wcat + (long)j * 256 + kg * 8;
    float bias[4];
#pragma unroll
    for (int g = 0; g < 4; ++g) bias[g] = Bsum[g * H + j];

    // staging: fi = i*512 + t -> row = fi>>5 (0..31), kv = fi&31 (float4 index)
    const int s_row0 = t >> 5;
    const int s_row1 = (512 + t) >> 5;
    const int s_kv = t & 31;

    float4 sx[2], sh[2];
    float cp[8];
    const long c_off = (long)B_ROWS * H;

    // issue tile 0 staging loads
    {
        long r0 = base;
        sx[0] = *(const float4*)(X  + (r0 + s_row0) * H + s_kv * 4);
        sh[0] = *(const float4*)(Hp + (r0 + s_row0) * H + s_kv * 4);
        sx[1] = *(const float4*)(X  + (r0 + s_row1) * H + s_kv * 4);
        sh[1] = *(const float4*)(Hp + (r0 + s_row1) * H + s_kv * 4);
    }

    for (int tile = 0; tile < TILES; ++tile) {
        const long r0 = base + tile * BM;
        char* lbuf = lds[tile & 1];

        // ---- write staged regs to LDS (bf16, swizzled) ----
#pragma unroll
        for (int i = 0; i < 2; ++i) {
            int row = (i == 0) ? s_row0 : s_row1;
            int swz = (row & 7) << 4;
            union { __bf16 b[4]; unsigned long long u; } px, ph;
            float4 vx = sx[i], vh = sh[i];
            px.b[0] = (__bf16)vx.x; px.b[1] = (__bf16)vx.y;
            px.b[2] = (__bf16)vx.z; px.b[3] = (__bf16)vx.w;
            ph.b[0] = (__bf16)vh.x; ph.b[1] = (__bf16)vh.y;
            ph.b[2] = (__bf16)vh.z; ph.b[3] = (__bf16)vh.w;
            *(unsigned long long*)(lbuf + row * 512 + ((s_kv * 8) ^ swz)) = px.u;
            *(unsigned long long*)(lbuf + row * 512 + ((256 + s_kv * 8) ^ swz)) = ph.u;
        }

        // ---- issue epilogue c_prev loads for THIS tile (hide under MFMA) ----
#pragma unroll
        for (int rt = 0; rt < 2; ++rt)
#pragma unroll
            for (int r = 0; r < 4; ++r)
                cp[rt * 4 + r] = Cp[(r0 + rt * 16 + kg * 4 + r) * H + j];

        __syncthreads();

        // ---- issue NEXT tile staging loads (overlap with compute) ----
        if (tile + 1 < TILES) {
            long rn = r0 + BM;
            sx[0] = *(const float4*)(X  + (rn + s_row0) * H + s_kv * 4);
            sh[0] = *(const float4*)(Hp + (rn + s_row0) * H + s_kv * 4);
            sx[1] = *(const float4*)(X  + (rn + s_row1) * H + s_kv * 4);
            sh[1] = *(const float4*)(Hp + (rn + s_row1) * H + s_kv * 4);
        }

        // ---- MFMA: 8 K-chunks x 4 gates x 2 row-tiles ----
        f32x4 acc[4][2] = {};
#pragma unroll
        for (int kc = 0; kc < 8; ++kc) {
            bf16x8 a[2];
#pragma unroll
            for (int rt = 0; rt < 2; ++rt) {
                int row = rt * 16 + l16;
                int off = row * 512 + ((kc * 64 + kg * 16) ^ ((row & 7) << 4));
                a[rt] = *(const bf16x8*)(lbuf + off);
            }
#pragma unroll
            for (int g = 0; g < 4; ++g) {
                bf16x8 b = *(const bf16x8*)(wbase + g * (128 * 256) + kc * 32);
                acc[g][0] = __builtin_amdgcn_mfma_f32_16x16x32_bf16(a[0], b, acc[g][0], 0, 0, 0);
                acc[g][1] = __builtin_amdgcn_mfma_f32_16x16x32_bf16(a[1], b, acc[g][1], 0, 0, 0);
            }
        }

        // ---- epilogue: bias + activations, all gates lane-local ----
#pragma unroll
        for (int rt = 0; rt < 2; ++rt) {
#pragma unroll
            for (int r = 0; r < 4; ++r) {
                long row = r0 + rt * 16 + kg * 4 + r;   // C/D layout: row=(lane>>4)*4+reg
                float f  = acc[0][rt][r] + bias[0];
                float ii = acc[1][rt][r] + bias[1];
                float cl = acc[2][rt][r] + bias[2];
                float oo = acc[3][rt][r] + bias[3];
                float ft = 1.0f / (1.0f + __expf(-f));
                float it = 1.0f / (1.0f + __expf(-ii));
                float cc = 1.0f - 2.0f / (__expf(2.0f * cl) + 1.0f);
                float ot = 1.0f / (1.0f + __expf(-oo));
                float ct = ft * cp[rt * 4 + r] + it * cc;
                float th = 1.0f - 2.0f / (__expf(2.0f * ct) + 1.0f);
                out[row * H + j] = ot * th;
                out[c_off + row * H + j] = ct;
            }
        }
        // no trailing barrier needed: next iteration writes the OTHER LDS buffer,
        // and the t+2 overwrite of this buffer is fenced by iteration t+1's barrier.
    }
}

extern "C" void kernel_launch(void* const* d_in, const int* in_sizes, int n_in,
                              void* d_out, int out_size, void* d_ws, size_t ws_size,
                              hipStream_t stream) {
    const float* X  = (const float*)d_in[0];
    const float* Hp = (const float*)d_in[1];
    const float* Cp = (const float*)d_in[2];
    WPtrs p;
    p.wx[0] = (const float*)d_in[3];  p.bx[0] = (const float*)d_in[4];
    p.wh[0] = (const float*)d_in[5];  p.bh[0] = (const float*)d_in[6];
    p.wx[1] = (const float*)d_in[7];  p.bx[1] = (const float*)d_in[8];
    p.wh[1] = (const float*)d_in[9];  p.bh[1] = (const float*)d_in[10];
    p.wx[2] = (const float*)d_in[11]; p.bx[2] = (const float*)d_in[12];
    p.wh[2] = (const float*)d_in[13]; p.bh[2] = (const float*)d_in[14];
    p.wx[3] = (const float*)d_in[15]; p.bx[3] = (const float*)d_in[16];
    p.wh[3] = (const float*)d_in[17]; p.bh[3] = (const float*)d_in[18];

    __bf16* wcat = (__bf16*)d_ws;
    float*  bsum = (float*)((char*)d_ws + 512 * 256 * 2);

    prep_weights<<<512, 256, 0, stream>>>(p, wcat, bsum);
    lstm_fused<<<NBLK, 512, 0, stream>>>(X, Hp, Cp, wcat, bsum, (float*)d_out);
}

// Round 3
// 98.355 us; speedup vs baseline: 2.2712x; 2.2712x over previous
//
#include <hip/hip_runtime.h>
#include <hip/hip_bf16.h>

#define B_ROWS 131072
#define H 128
#define BM 32
#define TILES 8
#define NBLK (B_ROWS / (BM * TILES))   // 512 blocks

typedef __bf16 bf16x8 __attribute__((ext_vector_type(8)));
typedef float f32x4 __attribute__((ext_vector_type(4)));

struct WPtrs {
    const float* wx[4];
    const float* wh[4];
    const float* bx[4];
    const float* bh[4];
};

// Wcat[n][k]: n = gate*128 + hidden_unit, k in [0,256) = [X-k | h-k]. bsum[n] = bx+bh.
__global__ __launch_bounds__(256) void prep_weights(WPtrs p, __bf16* __restrict__ wcat,
                                                    float* __restrict__ bsum) {
    int n = blockIdx.x;      // 0..511
    int k = threadIdx.x;     // 0..255
    int g = n >> 7, r = n & 127;
    float v = (k < H) ? p.wx[g][r * H + k] : p.wh[g][r * H + (k - H)];
    wcat[n * 256 + k] = (__bf16)v;
    if (k == 0) bsum[n] = p.bx[g][r] + p.bh[g][r];
}

__global__ __launch_bounds__(512, 2) void lstm_fused(
    const float* __restrict__ X, const float* __restrict__ Hp, const float* __restrict__ Cp,
    const __bf16* __restrict__ Wcat, const float* __restrict__ Bsum,
    float* __restrict__ out)
{
    __shared__ char alds[BM * 512];          // 16 KB bf16 [X|h] tile, XOR-swizzled
    __shared__ float glds[4][BM][132];       // 67.6 KB gates (pad 132 keeps 16B-aligned rows, breaks conflicts)

    const int t = threadIdx.x;
    const int lane = t & 63;
    const int wv = t >> 6;                   // wave 0..7 -> hidden cols [wv*16, wv*16+16)
    const int l16 = lane & 15;
    const int kg = lane >> 4;                // 0..3
    const long base = (long)blockIdx.x * (BM * TILES);
    const long c_off = (long)B_ROWS * H;

    const int j = wv * 16 + l16;             // this lane's hidden column (B-frag col)

    // ---- weights -> registers, once (L2-resident 256 KB) ----
    bf16x8 wreg[4][8];
    {
        const __bf16* wb = Wcat + (long)j * 256 + kg * 8;
#pragma unroll
        for (int g = 0; g < 4; ++g)
#pragma unroll
            for (int kc = 0; kc < 8; ++kc)
                wreg[g][kc] = *(const bf16x8*)(wb + g * (128 * 256) + kc * 32);
    }
    float bias[4];
#pragma unroll
    for (int g = 0; g < 4; ++g) bias[g] = Bsum[g * H + j];

    // coalesced staging map: thread t handles rows r_q0 / r_q1, float4-col c4
    const int r_q0 = t >> 5;                 // 0..15
    const int r_q1 = 16 + (t >> 5);          // 16..31
    const int c4 = t & 31;

    float4 sx[2], sh[2], scp[2];

    // prologue: issue tile-0 X/Hp loads
    sx[0] = *(const float4*)(X  + (base + r_q0) * H + c4 * 4);
    sh[0] = *(const float4*)(Hp + (base + r_q0) * H + c4 * 4);
    sx[1] = *(const float4*)(X  + (base + r_q1) * H + c4 * 4);
    sh[1] = *(const float4*)(Hp + (base + r_q1) * H + c4 * 4);

    for (int tile = 0; tile < TILES; ++tile) {
        const long r0 = base + tile * BM;

        // ---- write staged regs -> LDS A-tile (bf16, swizzled) ----
#pragma unroll
        for (int q = 0; q < 2; ++q) {
            int row = q ? r_q1 : r_q0;
            int swz = (row & 7) << 4;
            union { __bf16 b[4]; unsigned long long u; } px, ph;
            float4 vx = sx[q], vh = sh[q];
            px.b[0] = (__bf16)vx.x; px.b[1] = (__bf16)vx.y;
            px.b[2] = (__bf16)vx.z; px.b[3] = (__bf16)vx.w;
            ph.b[0] = (__bf16)vh.x; ph.b[1] = (__bf16)vh.y;
            ph.b[2] = (__bf16)vh.z; ph.b[3] = (__bf16)vh.w;
            *(unsigned long long*)(alds + row * 512 + ((c4 * 8) ^ swz)) = px.u;
            *(unsigned long long*)(alds + row * 512 + ((256 + c4 * 8) ^ swz)) = ph.u;
        }
        __syncthreads();

        // ---- prefetch: NEXT tile X/Hp; THIS tile Cp (coalesced, hidden under MFMA) ----
        if (tile + 1 < TILES) {
            long rn = r0 + BM;
            sx[0] = *(const float4*)(X  + (rn + r_q0) * H + c4 * 4);
            sh[0] = *(const float4*)(Hp + (rn + r_q0) * H + c4 * 4);
            sx[1] = *(const float4*)(X  + (rn + r_q1) * H + c4 * 4);
            sh[1] = *(const float4*)(Hp + (rn + r_q1) * H + c4 * 4);
        }
        scp[0] = *(const float4*)(Cp + (r0 + r_q0) * H + c4 * 4);
        scp[1] = *(const float4*)(Cp + (r0 + r_q1) * H + c4 * 4);

        // ---- MFMA: weights stationary in regs, A from LDS ----
        f32x4 acc[4][2] = {};
#pragma unroll
        for (int kc = 0; kc < 8; ++kc) {
            bf16x8 a[2];
#pragma unroll
            for (int rt = 0; rt < 2; ++rt) {
                int row = rt * 16 + l16;
                int off = row * 512 + ((kc * 64 + kg * 16) ^ ((row & 7) << 4));
                a[rt] = *(const bf16x8*)(alds + off);
            }
#pragma unroll
            for (int g = 0; g < 4; ++g) {
                acc[g][0] = __builtin_amdgcn_mfma_f32_16x16x32_bf16(a[0], wreg[g][kc], acc[g][0], 0, 0, 0);
                acc[g][1] = __builtin_amdgcn_mfma_f32_16x16x32_bf16(a[1], wreg[g][kc], acc[g][1], 0, 0, 0);
            }
        }

        // ---- gates -> LDS (per-lane scatter; C/D layout row=(lane>>4)*4+reg, col=lane&15) ----
#pragma unroll
        for (int g = 0; g < 4; ++g)
#pragma unroll
            for (int rt = 0; rt < 2; ++rt)
#pragma unroll
                for (int r = 0; r < 4; ++r)
                    glds[g][rt * 16 + kg * 4 + r][j] = acc[g][rt][r] + bias[g];
        __syncthreads();

        // ---- epilogue: fully coalesced float4 rows ----
#pragma unroll
        for (int q = 0; q < 2; ++q) {
            int row = q ? r_q1 : r_q0;
            f32x4 fv = *(const f32x4*)&glds[0][row][c4 * 4];
            f32x4 iv = *(const f32x4*)&glds[1][row][c4 * 4];
            f32x4 cv = *(const f32x4*)&glds[2][row][c4 * 4];
            f32x4 ov = *(const f32x4*)&glds[3][row][c4 * 4];
            float4 cp = scp[q];
            float cpa[4] = {cp.x, cp.y, cp.z, cp.w};
            float4 ho, co;
            float* hp = &ho.x;
            float* cw = &co.x;
#pragma unroll
            for (int r = 0; r < 4; ++r) {
                float ft = 1.0f / (1.0f + __expf(-fv[r]));
                float it = 1.0f / (1.0f + __expf(-iv[r]));
                float cc = 1.0f - 2.0f / (__expf(2.0f * cv[r]) + 1.0f);
                float ot = 1.0f / (1.0f + __expf(-ov[r]));
                float ct = ft * cpa[r] + it * cc;
                float th = 1.0f - 2.0f / (__expf(2.0f * ct) + 1.0f);
                hp[r] = ot * th;
                cw[r] = ct;
            }
            *(float4*)(out + (r0 + row) * H + c4 * 4) = ho;
            *(float4*)(out + c_off + (r0 + row) * H + c4 * 4) = co;
        }
        // no 3rd barrier: next tile's glds writes are fenced by its first __syncthreads
    }
}

extern "C" void kernel_launch(void* const* d_in, const int* in_sizes, int n_in,
                              void* d_out, int out_size, void* d_ws, size_t ws_size,
                              hipStream_t stream) {
    const float* X  = (const float*)d_in[0];
    const float* Hp = (const float*)d_in[1];
    const float* Cp = (const float*)d_in[2];
    WPtrs p;
    p.wx[0] = (const float*)d_in[3];  p.bx[0] = (const float*)d_in[4];
    p.wh[0] = (const float*)d_in[5];  p.bh[0] = (const float*)d_in[6];
    p.wx[1] = (const float*)d_in[7];  p.bx[1] = (const float*)d_in[8];
    p.wh[1] = (const float*)d_in[9];  p.bh[1] = (const float*)d_in[10];
    p.wx[2] = (const float*)d_in[11]; p.bx[2] = (const float*)d_in[12];
    p.wh[2] = (const float*)d_in[13]; p.bh[2] = (const float*)d_in[14];
    p.wx[3] = (const float*)d_in[15]; p.bx[3] = (const float*)d_in[16];
    p.wh[3] = (const float*)d_in[17]; p.bh[3] = (const float*)d_in[18];

    __bf16* wcat = (__bf16*)d_ws;
    float*  bsum = (float*)((char*)d_ws + 512 * 256 * 2);

    prep_weights<<<512, 256, 0, stream>>>(p, wcat, bsum);
    lstm_fused<<<NBLK, 512, 0, stream>>>(X, Hp, Cp, wcat, bsum, (float*)d_out);
}